// Round 3
// baseline (954.416 us; speedup 1.0000x reference)
//
#include <hip/hip_runtime.h>
#include <stdint.h>

#define THREADS 256
#define N_MAX 131072
#define B_MAX 2100000
#define SF_UNROLL 4

// Static device scratch (n <= 131072 nodes, totalBlocks = n+2E <= 2.1M).
// g_cnt / g_cnt2 are self-restoring: hist counts UP, scatter_fill claims slots by
// atomicSub counting DOWN to exactly zero -> no zero_kernel needed between calls.
__device__ int g_cnt[N_MAX];        // blocks per node (row/col histogram over E)
__device__ int g_cnt2[N_MAX];       // diag contributions per node (histogram of ei[0] over 2E)
__device__ int g_blk_off[N_MAX + 1];
__device__ int g_off2[N_MAX + 1];
__device__ float g_maps_diag[(size_t)N_MAX * 16];
__device__ unsigned long long g_keys[B_MAX];
__device__ int g_perm[B_MAX];       // counting-sort of g in [0,2E) by ei[0][g]
__device__ int g_wide;

// edge_index staged int32 or int64 (values < 2^31, LE): wide==1 -> low word at 2*idx.
__device__ __forceinline__ int get_ei(const int* __restrict__ ei, int wide, long long idx) {
  return ei[idx << wide];
}

__device__ __forceinline__ unsigned long long shfl_xor_u64(unsigned long long x, int mask) {
  int lo = (int)(x & 0xFFFFFFFFULL);
  int hi = (int)(x >> 32);
  lo = __shfl_xor(lo, mask, 64);
  hi = __shfl_xor(hi, mask, 64);
  return ((unsigned long long)(unsigned int)hi << 32) | (unsigned int)lo;
}

// 1) histograms + in-block wide detection (removes the 1-thread detect_wide launch).
__global__ void hist_kernel(const int* __restrict__ ei, int E, int twoE) {
  __shared__ int s_w;
  if (threadIdx.x == 0) {
    int w = 1;
    int lim = (twoE >= 8) ? 8 : twoE;
    for (int i = 0; i < lim; i++)
      if (ei[2 * i + 1] != 0) w = 0;
    s_w = w;
    if (blockIdx.x == 0) g_wide = w;   // for downstream dispatches
  }
  __syncthreads();
  int w = s_w;
  int g = blockIdx.x * blockDim.x + threadIdx.x;
  if (g >= twoE) return;
  int a0 = get_ei(ei, w, g);
  atomicAdd(&g_cnt2[a0], 1);
  if (g < E) {
    atomicAdd(&g_cnt[a0], 1);                                  // row
    atomicAdd(&g_cnt[get_ei(ei, w, (long long)twoE + g)], 1);  // col
  }
}

// 2) both exclusive scans in ONE launch: block 0 -> blk_off (cnt+1), block 1 -> off2 (cnt2)
__global__ void scan_kernel(int n) {
  __shared__ int partial[1024];
  int which = blockIdx.x;
  int tid = threadIdx.x;
  int chunk = (n + 1023) / 1024;
  int start = tid * chunk;
  int end = min(start + chunk, n);
  int add1 = (which == 0) ? 1 : 0;
  const int* src = (which == 0) ? g_cnt : g_cnt2;
  int* dst = (which == 0) ? g_blk_off : g_off2;
  int s = 0;
  for (int u = start; u < end; u++) s += src[u] + add1;
  partial[tid] = s;
  __syncthreads();
  for (int off = 1; off < 1024; off <<= 1) {
    int v = (tid >= off) ? partial[tid - off] : 0;
    __syncthreads();
    partial[tid] += v;
    __syncthreads();
  }
  int run = (tid == 0) ? 0 : partial[tid - 1];
  for (int u = start; u < end; u++) { dst[u] = run; run += src[u] + add1; }
  if (tid == 1023) dst[n] = partial[1023];
}

// 3) merged counting-sort scatter (perm) + edge key fill, 4 edges per thread with
//    phase-ordered independent atomic chains (4x memory-level parallelism against
//    ~700cy device-scope atomic latency). Slots claimed by atomicSub counting the
//    histograms back down to zero (self-restoring scratch).
//    key = (u << 44) | (v << 22) | (cls << 20) | e   (u,v < 2^17, e < 2^20)
__global__ void scatter_fill_kernel(const int* __restrict__ ei, int E, int twoE) {
  int w = g_wide;
  int tile = blockIdx.x * (THREADS * SF_UNROLL);
  int g[SF_UNROLL], u[SF_UNROLL], p[SF_UNROLL];
  bool ok[SF_UNROLL];
  // phase 1: coalesced u loads
#pragma unroll
  for (int k = 0; k < SF_UNROLL; k++) {
    g[k] = tile + k * THREADS + threadIdx.x;
    ok[k] = g[k] < twoE;
    u[k] = ok[k] ? get_ei(ei, w, g[k]) : 0;
  }
  // phase 2: perm slot claims (4 independent atomic round-trips in flight)
#pragma unroll
  for (int k = 0; k < SF_UNROLL; k++)
    if (ok[k]) p[k] = g_off2[u[k]] + atomicSub(&g_cnt2[u[k]], 1) - 1;
#pragma unroll
  for (int k = 0; k < SF_UNROLL; k++)
    if (ok[k]) g_perm[p[k]] = g[k];
  // phase 3: edge-key path (first E only)
  int v[SF_UNROLL], c1[SF_UNROLL], c2[SF_UNROLL];
  bool ev[SF_UNROLL];
#pragma unroll
  for (int k = 0; k < SF_UNROLL; k++) {
    ev[k] = g[k] < E;
    v[k] = ev[k] ? get_ei(ei, w, (long long)twoE + g[k]) : 0;
  }
#pragma unroll
  for (int k = 0; k < SF_UNROLL; k++)
    if (ev[k]) c1[k] = atomicSub(&g_cnt[u[k]], 1);   // old value in [1, cnt[u]]
#pragma unroll
  for (int k = 0; k < SF_UNROLL; k++)
    if (ev[k]) c2[k] = atomicSub(&g_cnt[v[k]], 1);
#pragma unroll
  for (int k = 0; k < SF_UNROLL; k++)
    if (ev[k]) {
      int p1 = g_blk_off[u[k]] + c1[k];              // diag slot is +0
      g_keys[p1] = ((unsigned long long)u[k] << 44) | ((unsigned long long)v[k] << 22) |
                   (1ULL << 20) | (unsigned long long)g[k];
      int p2 = g_blk_off[v[k]] + c2[k];
      g_keys[p2] = ((unsigned long long)v[k] << 44) | ((unsigned long long)u[k] << 22) |
                   (2ULL << 20) | (unsigned long long)g[k];
    }
}

// 4) gather-reduce diag, 16 threads per node (16n threads -> full occupancy for the
//    102 MB random-line gather), shfl-combine over the 16-lane group, lane h==0 also
//    places the diag key (place_diag merged).
__global__ void diag_place_kernel(const float* __restrict__ maps, int n) {
  int t = blockIdx.x * blockDim.x + threadIdx.x;
  int u = t >> 4;
  int h = t & 15;
  if (u >= n) return;
  int s = g_off2[u];
  int epos = g_off2[u + 1];
  float acc[10];
#pragma unroll
  for (int i = 0; i < 10; i++) acc[i] = 0.0f;
  for (int i = s + h; i < epos; i += 16) {
    int g = g_perm[i];
    const float4* Mv = reinterpret_cast<const float4*>(maps + (size_t)g * 16);
    float4 t0 = Mv[0], t1 = Mv[1], t2 = Mv[2], t3 = Mv[3];
    float m[16] = {t0.x, t0.y, t0.z, t0.w, t1.x, t1.y, t1.z, t1.w,
                   t2.x, t2.y, t2.z, t2.w, t3.x, t3.y, t3.z, t3.w};
    int p = 0;
#pragma unroll
    for (int a = 0; a < 4; a++)
#pragma unroll
      for (int b = a; b < 4; b++) {
        acc[p] += m[0 + a] * m[0 + b] + m[4 + a] * m[4 + b] + m[8 + a] * m[8 + b] + m[12 + a] * m[12 + b];
        p++;
      }
  }
#pragma unroll
  for (int i = 0; i < 10; i++) {
    acc[i] += __shfl_xor(acc[i], 1, 64);
    acc[i] += __shfl_xor(acc[i], 2, 64);
    acc[i] += __shfl_xor(acc[i], 4, 64);
    acc[i] += __shfl_xor(acc[i], 8, 64);
  }
  if (h == 0) {
    float d[16];
    int p = 0;
#pragma unroll
    for (int a = 0; a < 4; a++)
#pragma unroll
      for (int b = a; b < 4; b++) {
        d[a * 4 + b] = acc[p];
        d[b * 4 + a] = acc[p];
        p++;
      }
    float4* D = reinterpret_cast<float4*>(g_maps_diag + (size_t)u * 16);
#pragma unroll
    for (int i = 0; i < 4; i++) D[i] = make_float4(d[4 * i], d[4 * i + 1], d[4 * i + 2], d[4 * i + 3]);
    int pp = g_blk_off[u];
    g_keys[pp] = ((unsigned long long)u << 44) | ((unsigned long long)u << 22);
  }
}

// 5) per-node sort: ONE WAVE per node, register bitonic via shfl_xor.
//    c<=64: 1 reg/lane, 21 compare-exchange steps. c<=128: 2 regs/lane, 28 steps.
//    No LDS, no divergent dependent-latency chains, coalesced key IO.
__global__ __launch_bounds__(256) void sort_kernel(int n) {
  int wv = (blockIdx.x * blockDim.x + threadIdx.x) >> 6;  // node = global wave id
  int lane = threadIdx.x & 63;
  if (wv >= n) return;
  int s = g_blk_off[wv];
  int c = g_blk_off[wv + 1] - s;
  if (c <= 1) return;
  if (c <= 64) {
    unsigned long long k = (lane < c) ? g_keys[s + lane] : ~0ULL;
    for (int kk = 2; kk <= 64; kk <<= 1) {
      for (int j = kk >> 1; j > 0; j >>= 1) {
        unsigned long long o = shfl_xor_u64(k, j);
        bool tm = ((lane & j) == 0) == ((lane & kk) == 0);
        unsigned long long lo = (k < o) ? k : o;
        unsigned long long hi = (k < o) ? o : k;
        k = tm ? lo : hi;
      }
    }
    if (lane < c) g_keys[s + lane] = k;
  } else if (c <= 128) {
    unsigned long long k0 = (lane < c) ? g_keys[s + lane] : ~0ULL;
    unsigned long long k1 = (lane + 64 < c) ? g_keys[s + lane + 64] : ~0ULL;
    for (int kk = 2; kk <= 128; kk <<= 1) {
      for (int j = kk >> 1; j > 0; j >>= 1) {
        if (j == 64) {  // only at kk==128: virtual lane < 64 takes min (all ascending)
          unsigned long long lo = (k0 < k1) ? k0 : k1;
          unsigned long long hi = (k0 < k1) ? k1 : k0;
          k0 = lo; k1 = hi;
        } else {
          unsigned long long o0 = shfl_xor_u64(k0, j);
          unsigned long long o1 = shfl_xor_u64(k1, j);
          bool jb = ((lane & j) == 0);
          bool tm0 = jb == ((lane & kk) == 0);
          bool tm1 = jb == (((lane + 64) & kk) == 0);
          unsigned long long lo0 = (k0 < o0) ? k0 : o0;
          unsigned long long hi0 = (k0 < o0) ? o0 : k0;
          unsigned long long lo1 = (k1 < o1) ? k1 : o1;
          unsigned long long hi1 = (k1 < o1) ? o1 : k1;
          k0 = tm0 ? lo0 : hi0;
          k1 = tm1 ? lo1 : hi1;
        }
      }
    }
    if (lane < c) g_keys[s + lane] = k0;
    if (lane + 64 < c) g_keys[s + lane + 64] = k1;
  } else {  // essentially-never fallback (Poisson(~33) degree)
    if (lane == 0) {
      for (int i = s + 1; i < s + c; i++) {
        unsigned long long kk2 = g_keys[i];
        int j = i - 1;
        while (j >= s && g_keys[j] > kk2) { g_keys[j + 1] = g_keys[j]; j--; }
        g_keys[j + 1] = kk2;
      }
    }
  }
}

// 6) emit (float32 out): one thread per block; b-major interleave for equal-v runs.
//    u decoded from key high bits (g_blk_node eliminated).
__global__ void emit_kernel(const float* __restrict__ maps, int E, long long T, int totalBlocks,
                            float* __restrict__ out) {
  int idx = blockIdx.x * blockDim.x + threadIdx.x;
  if (idx >= totalBlocks) return;
  unsigned long long key = g_keys[idx];
  int u = (int)(key >> 44);
  int base = g_blk_off[u];
  int cntu = g_blk_off[u + 1] - base;
  int k = idx - base;
  int v = (int)((key >> 22) & 0x3FFFFFULL);
  int cls = (int)((key >> 20) & 3ULL);
  int e = (int)(key & 0xFFFFFULL);
  unsigned long long vtag = key >> 22;  // (u,v) tag: u bits identical within node

  int k0 = k;
  while (k0 > 0 && (g_keys[base + k0 - 1] >> 22) == vtag) k0--;
  int k1 = k;
  while (k1 + 1 < cntu && (g_keys[base + k1 + 1] >> 22) == vtag) k1++;
  int m = k1 - k0 + 1;
  int j = k - k0;

  float val[16];
  if (cls == 0) {
    const float* D = g_maps_diag + (size_t)u * 16;
#pragma unroll
    for (int i = 0; i < 16; i++) val[i] = D[i];
  } else {
    const float* L = maps + (size_t)e * 16;
    const float* R = maps + ((size_t)E + (size_t)e) * 16;
    float l[16], r[16];
#pragma unroll
    for (int i = 0; i < 16; i++) { l[i] = L[i]; r[i] = R[i]; }
    if (cls == 1) {
#pragma unroll
      for (int a = 0; a < 4; a++)
#pragma unroll
        for (int b = 0; b < 4; b++)
          val[a * 4 + b] = -(l[0 + a] * r[0 + b] + l[4 + a] * r[4 + b] + l[8 + a] * r[8 + b] + l[12 + a] * r[12 + b]);
    } else {
#pragma unroll
      for (int a = 0; a < 4; a++)
#pragma unroll
        for (int b = 0; b < 4; b++)
          val[a * 4 + b] = -(l[0 + b] * r[0 + a] + l[4 + b] * r[4 + a] + l[8 + b] * r[8 + a] + l[12 + b] * r[12 + a]);
    }
  }

  float* orow = out;
  float* ocol = out + T;
  float* oval = out + 2 * T;
  long long blkbase = 16LL * base + 4LL * k0;
  float cf = (float)(v * 4);
#pragma unroll
  for (int a = 0; a < 4; a++) {
    long long rowbase = blkbase + (long long)a * 4 * cntu;
    float rf = (float)(u * 4 + a);
    if (m == 1) {
      *reinterpret_cast<float4*>(orow + rowbase) = make_float4(rf, rf, rf, rf);
      *reinterpret_cast<float4*>(ocol + rowbase) = make_float4(cf, cf + 1.0f, cf + 2.0f, cf + 3.0f);
      *reinterpret_cast<float4*>(oval + rowbase) =
          make_float4(val[a * 4 + 0], val[a * 4 + 1], val[a * 4 + 2], val[a * 4 + 3]);
    } else {
#pragma unroll
      for (int b = 0; b < 4; b++) {
        long long pos = rowbase + (long long)b * m + j;
        orow[pos] = rf;
        ocol[pos] = cf + (float)b;
        oval[pos] = val[a * 4 + b];
      }
    }
  }
}

extern "C" void kernel_launch(void* const* d_in, const int* in_sizes, int n_in,
                              void* d_out, int out_size, void* d_ws, size_t ws_size,
                              hipStream_t stream) {
  const float* maps = (const float*)d_in[0];
  const int* ei = (const int*)d_in[1];

  long long twoE = (long long)in_sizes[1] / 2;   // edge_index is (2, 2E)
  long long E = twoE / 2;
  long long T = (long long)out_size / 3;         // [rows(T), cols(T), vals(T)], float32
  long long totalBlocks = T / 16;                // n + 2E
  long long n = totalBlocks - twoE;
  if (n < 1 || n > N_MAX || totalBlocks > B_MAX || twoE > B_MAX) return;

  int iE = (int)E, i2E = (int)twoE, iN = (int)n, iB = (int)totalBlocks;
  int g2E = (i2E + THREADS - 1) / THREADS;
  int gSF = (i2E + THREADS * SF_UNROLL - 1) / (THREADS * SF_UNROLL);
  int gD = (16 * iN + THREADS - 1) / THREADS;
  int gSort = (iN + 3) / 4;                      // 4 waves (nodes) per 256-thread block
  int gB = (iB + THREADS - 1) / THREADS;

  hist_kernel<<<g2E, THREADS, 0, stream>>>(ei, iE, i2E);
  scan_kernel<<<2, 1024, 0, stream>>>(iN);
  scatter_fill_kernel<<<gSF, THREADS, 0, stream>>>(ei, iE, i2E);
  diag_place_kernel<<<gD, THREADS, 0, stream>>>(maps, iN);
  sort_kernel<<<gSort, 256, 0, stream>>>(iN);
  emit_kernel<<<gB, THREADS, 0, stream>>>(maps, iE, T, iB, (float*)d_out);
}

// Round 4
// 877.939 us; speedup vs baseline: 1.0871x; 1.0871x over previous
//
#include <hip/hip_runtime.h>
#include <stdint.h>

#define THREADS 256
#define N_MAX 131072
#define B_MAX 2100000

// Static device scratch (n <= 131072 nodes, totalBlocks = n+2E <= 2.1M).
// g_packed is self-restoring: hist counts UP, scatter_fill claims slots by atomicSub
// counting DOWN to exactly zero -> no zero kernel. high16 = cnt (key records per node),
// low16 = cnt2 (second-half diag contribs per node). Halves never borrow: each half is
// decremented exactly as many times as it was incremented, and each sub touches one half.
__device__ int g_packed[N_MAX];
__device__ int g_blk_off[N_MAX + 1];   // excl scan of (cnt+1)
__device__ int g_off2[N_MAX + 1];      // excl scan of cnt2
__device__ float g_maps_diag[(size_t)N_MAX * 16];
__device__ unsigned long long g_keys[B_MAX];
__device__ int g_perm2[B_MAX];         // g in [E,2E) grouped by src(g) (diag part B)
__device__ int g_wide;

// edge_index staged int32 or int64 (values < 2^31, LE): wide==1 -> low word at 2*idx.
__device__ __forceinline__ int get_ei(const int* __restrict__ ei, int wide, long long idx) {
  return ei[idx << wide];
}

__device__ __forceinline__ unsigned long long shfl_xor_u64(unsigned long long x, int mask) {
  int lo = (int)(x & 0xFFFFFFFFULL);
  int hi = (int)(x >> 32);
  lo = __shfl_xor(lo, mask, 64);
  hi = __shfl_xor(hi, mask, 64);
  return ((unsigned long long)(unsigned int)hi << 32) | (unsigned int)lo;
}

// 1) histogram + in-block wide detection. Per g<E: cnt[src]++, cnt[dst]++ (key records).
//    Per g>=E: cnt2[src]++ (diag part-B). 2.4M fire-and-forget atomics (was 3.2M).
__global__ void hist_kernel(const int* __restrict__ ei, int E, int twoE) {
  __shared__ int s_w;
  if (threadIdx.x == 0) {
    int w = 1;
    int lim = (twoE >= 8) ? 8 : twoE;
    for (int i = 0; i < lim; i++)
      if (ei[2 * i + 1] != 0) w = 0;
    s_w = w;
    if (blockIdx.x == 0) g_wide = w;   // for downstream dispatches
  }
  __syncthreads();
  int w = s_w;
  int g = blockIdx.x * blockDim.x + threadIdx.x;
  if (g >= twoE) return;
  int s0 = get_ei(ei, w, g);           // src(g)
  if (g < E) {
    atomicAdd(&g_packed[s0], 1 << 16);                                      // ij at src(e)
    atomicAdd(&g_packed[get_ei(ei, w, (long long)twoE + g)], 1 << 16);      // ji at dst(e)
  } else {
    atomicAdd(&g_packed[s0], 1);                                            // cnt2 at src(g)
  }
}

// 2) both exclusive scans in ONE launch: block 0 -> blk_off (cnt+1, high half),
//    block 1 -> off2 (cnt2, low half)
__global__ void scan_kernel(int n) {
  __shared__ int partial[1024];
  int which = blockIdx.x;
  int tid = threadIdx.x;
  int chunk = (n + 1023) / 1024;
  int start = tid * chunk;
  int end = min(start + chunk, n);
  int* dst = (which == 0) ? g_blk_off : g_off2;
  int s = 0;
  for (int u = start; u < end; u++) {
    int pk = g_packed[u];
    s += (which == 0) ? (int)(((unsigned)pk) >> 16) + 1 : (pk & 0xFFFF);
  }
  partial[tid] = s;
  __syncthreads();
  for (int off = 1; off < 1024; off <<= 1) {
    int v = (tid >= off) ? partial[tid - off] : 0;
    __syncthreads();
    partial[tid] += v;
    __syncthreads();
  }
  int run = (tid == 0) ? 0 : partial[tid - 1];
  for (int u = start; u < end; u++) {
    dst[u] = run;
    int pk = g_packed[u];
    run += (which == 0) ? (int)(((unsigned)pk) >> 16) + 1 : (pk & 0xFFFF);
  }
  if (tid == 1023) dst[n] = partial[1023];
}

// 3) scatter: ONE key record per thread (t(g)-mapping), perm2 only for second half.
//    g<E:  ij record at src(g)          -> 1 atomic-return + 1 scattered 8B store
//    g>=E: ji record for e=g-E at dst(e) + perm2 entry at src(g)
//                                        -> 2 atomic-returns + 8B + 4B scattered stores
//    Totals: 2.4M atomic-returns, 2.4M scattered stores (was 3.2M / 3.2M).
//    key = (u << 44) | (v << 22) | (cls << 20) | e   (u,v < 2^17, e < 2^20)
__global__ void scatter_fill_kernel(const int* __restrict__ ei, int E, int twoE) {
  int g = blockIdx.x * blockDim.x + threadIdx.x;
  if (g >= twoE) return;
  int w = g_wide;
  if (g < E) {
    int u = get_ei(ei, w, g);                      // src(e)
    int v = get_ei(ei, w, (long long)twoE + g);    // dst(e)
    int old = atomicSub(&g_packed[u], 1 << 16);
    int h = (int)(((unsigned)old) >> 16);          // in [1, cnt[u]]; diag slot is +0
    g_keys[g_blk_off[u] + h] = ((unsigned long long)u << 44) | ((unsigned long long)v << 22) |
                               (1ULL << 20) | (unsigned long long)g;
  } else {
    int e = g - E;
    int s2 = get_ei(ei, w, g);                     // src(g): perm2 home
    int ue = get_ei(ei, w, (long long)twoE + e);   // dst(e): ji record home
    int ve = get_ei(ei, w, e);                     // src(e): ji record's v
    int old1 = atomicSub(&g_packed[ue], 1 << 16);  // two independent atomics in flight
    int old2 = atomicSub(&g_packed[s2], 1);
    int h1 = (int)(((unsigned)old1) >> 16);
    g_keys[g_blk_off[ue] + h1] = ((unsigned long long)ue << 44) | ((unsigned long long)ve << 22) |
                                 (2ULL << 20) | (unsigned long long)e;
    g_perm2[g_off2[s2] + (old2 & 0xFFFF) - 1] = g; // absolute index into maps
  }
}

// 4) gather-reduce diag, 8 threads per node. Part A: u's own cls-1 key records
//    (linear read of u's region) give exactly {e<E: src(e)=u}. Part B: perm2 gives
//    {g in [E,2E): src(g)=u}. shfl-combine over the 8-lane group; lane h==0 writes
//    diag and places the diag key.
__global__ void diag_place_kernel(const float* __restrict__ maps, int n) {
  int t = blockIdx.x * blockDim.x + threadIdx.x;
  int u = t >> 3;
  int h = t & 7;
  if (u >= n) return;
  int kb = g_blk_off[u];
  int ke = g_blk_off[u + 1];
  float acc[10];
#pragma unroll
  for (int i = 0; i < 10; i++) acc[i] = 0.0f;
  // part A: cls-1 records in u's key region (slots kb+1 .. ke-1)
  for (int i = kb + 1 + h; i < ke; i += 8) {
    unsigned long long key = g_keys[i];
    if (((key >> 20) & 3ULL) == 1ULL) {
      int e = (int)(key & 0xFFFFFULL);
      const float4* Mv = reinterpret_cast<const float4*>(maps + (size_t)e * 16);
      float4 t0 = Mv[0], t1 = Mv[1], t2 = Mv[2], t3 = Mv[3];
      float m[16] = {t0.x, t0.y, t0.z, t0.w, t1.x, t1.y, t1.z, t1.w,
                     t2.x, t2.y, t2.z, t2.w, t3.x, t3.y, t3.z, t3.w};
      int p = 0;
#pragma unroll
      for (int a = 0; a < 4; a++)
#pragma unroll
        for (int b = a; b < 4; b++) {
          acc[p] += m[0 + a] * m[0 + b] + m[4 + a] * m[4 + b] + m[8 + a] * m[8 + b] + m[12 + a] * m[12 + b];
          p++;
        }
    }
  }
  // part B: second-half contributions via perm2
  int s2 = g_off2[u];
  int e2 = g_off2[u + 1];
  for (int i = s2 + h; i < e2; i += 8) {
    int g = g_perm2[i];
    const float4* Mv = reinterpret_cast<const float4*>(maps + (size_t)g * 16);
    float4 t0 = Mv[0], t1 = Mv[1], t2 = Mv[2], t3 = Mv[3];
    float m[16] = {t0.x, t0.y, t0.z, t0.w, t1.x, t1.y, t1.z, t1.w,
                   t2.x, t2.y, t2.z, t2.w, t3.x, t3.y, t3.z, t3.w};
    int p = 0;
#pragma unroll
    for (int a = 0; a < 4; a++)
#pragma unroll
      for (int b = a; b < 4; b++) {
        acc[p] += m[0 + a] * m[0 + b] + m[4 + a] * m[4 + b] + m[8 + a] * m[8 + b] + m[12 + a] * m[12 + b];
        p++;
      }
  }
#pragma unroll
  for (int i = 0; i < 10; i++) {
    acc[i] += __shfl_xor(acc[i], 1, 64);
    acc[i] += __shfl_xor(acc[i], 2, 64);
    acc[i] += __shfl_xor(acc[i], 4, 64);
  }
  if (h == 0) {
    float d[16];
    int p = 0;
#pragma unroll
    for (int a = 0; a < 4; a++)
#pragma unroll
      for (int b = a; b < 4; b++) {
        d[a * 4 + b] = acc[p];
        d[b * 4 + a] = acc[p];
        p++;
      }
    float4* D = reinterpret_cast<float4*>(g_maps_diag + (size_t)u * 16);
#pragma unroll
    for (int i = 0; i < 4; i++) D[i] = make_float4(d[4 * i], d[4 * i + 1], d[4 * i + 2], d[4 * i + 3]);
    g_keys[kb] = ((unsigned long long)u << 44) | ((unsigned long long)u << 22);
  }
}

// 5) per-node sort: ONE WAVE per node, register bitonic via shfl_xor.
//    c<=64: 1 reg/lane, 21 compare-exchange steps. c<=128: 2 regs/lane, 28 steps.
__global__ __launch_bounds__(256) void sort_kernel(int n) {
  int wv = (blockIdx.x * blockDim.x + threadIdx.x) >> 6;  // node = global wave id
  int lane = threadIdx.x & 63;
  if (wv >= n) return;
  int s = g_blk_off[wv];
  int c = g_blk_off[wv + 1] - s;
  if (c <= 1) return;
  if (c <= 64) {
    unsigned long long k = (lane < c) ? g_keys[s + lane] : ~0ULL;
    for (int kk = 2; kk <= 64; kk <<= 1) {
      for (int j = kk >> 1; j > 0; j >>= 1) {
        unsigned long long o = shfl_xor_u64(k, j);
        bool tm = ((lane & j) == 0) == ((lane & kk) == 0);
        unsigned long long lo = (k < o) ? k : o;
        unsigned long long hi = (k < o) ? o : k;
        k = tm ? lo : hi;
      }
    }
    if (lane < c) g_keys[s + lane] = k;
  } else if (c <= 128) {
    unsigned long long k0 = (lane < c) ? g_keys[s + lane] : ~0ULL;
    unsigned long long k1 = (lane + 64 < c) ? g_keys[s + lane + 64] : ~0ULL;
    for (int kk = 2; kk <= 128; kk <<= 1) {
      for (int j = kk >> 1; j > 0; j >>= 1) {
        if (j == 64) {  // only at kk==128: virtual lane < 64 takes min (all ascending)
          unsigned long long lo = (k0 < k1) ? k0 : k1;
          unsigned long long hi = (k0 < k1) ? k1 : k0;
          k0 = lo; k1 = hi;
        } else {
          unsigned long long o0 = shfl_xor_u64(k0, j);
          unsigned long long o1 = shfl_xor_u64(k1, j);
          bool jb = ((lane & j) == 0);
          bool tm0 = jb == ((lane & kk) == 0);
          bool tm1 = jb == (((lane + 64) & kk) == 0);
          unsigned long long lo0 = (k0 < o0) ? k0 : o0;
          unsigned long long hi0 = (k0 < o0) ? o0 : k0;
          unsigned long long lo1 = (k1 < o1) ? k1 : o1;
          unsigned long long hi1 = (k1 < o1) ? o1 : k1;
          k0 = tm0 ? lo0 : hi0;
          k1 = tm1 ? lo1 : hi1;
        }
      }
    }
    if (lane < c) g_keys[s + lane] = k0;
    if (lane + 64 < c) g_keys[s + lane + 64] = k1;
  } else {  // essentially-never fallback (Poisson(~33) degree)
    if (lane == 0) {
      for (int i = s + 1; i < s + c; i++) {
        unsigned long long kk2 = g_keys[i];
        int j = i - 1;
        while (j >= s && g_keys[j] > kk2) { g_keys[j + 1] = g_keys[j]; j--; }
        g_keys[j + 1] = kk2;
      }
    }
  }
}

// 6) emit (float32 out): one thread per block; b-major interleave for equal-v runs.
//    u decoded from key high bits.
__global__ void emit_kernel(const float* __restrict__ maps, int E, long long T, int totalBlocks,
                            float* __restrict__ out) {
  int idx = blockIdx.x * blockDim.x + threadIdx.x;
  if (idx >= totalBlocks) return;
  unsigned long long key = g_keys[idx];
  int u = (int)(key >> 44);
  int base = g_blk_off[u];
  int cntu = g_blk_off[u + 1] - base;
  int k = idx - base;
  int v = (int)((key >> 22) & 0x3FFFFFULL);
  int cls = (int)((key >> 20) & 3ULL);
  int e = (int)(key & 0xFFFFFULL);
  unsigned long long vtag = key >> 22;  // (u,v) tag: u bits identical within node

  int k0 = k;
  while (k0 > 0 && (g_keys[base + k0 - 1] >> 22) == vtag) k0--;
  int k1 = k;
  while (k1 + 1 < cntu && (g_keys[base + k1 + 1] >> 22) == vtag) k1++;
  int m = k1 - k0 + 1;
  int j = k - k0;

  float val[16];
  if (cls == 0) {
    const float* D = g_maps_diag + (size_t)u * 16;
#pragma unroll
    for (int i = 0; i < 16; i++) val[i] = D[i];
  } else {
    const float* L = maps + (size_t)e * 16;
    const float* R = maps + ((size_t)E + (size_t)e) * 16;
    float l[16], r[16];
#pragma unroll
    for (int i = 0; i < 16; i++) { l[i] = L[i]; r[i] = R[i]; }
    if (cls == 1) {
#pragma unroll
      for (int a = 0; a < 4; a++)
#pragma unroll
        for (int b = 0; b < 4; b++)
          val[a * 4 + b] = -(l[0 + a] * r[0 + b] + l[4 + a] * r[4 + b] + l[8 + a] * r[8 + b] + l[12 + a] * r[12 + b]);
    } else {
#pragma unroll
      for (int a = 0; a < 4; a++)
#pragma unroll
        for (int b = 0; b < 4; b++)
          val[a * 4 + b] = -(l[0 + b] * r[0 + a] + l[4 + b] * r[4 + a] + l[8 + b] * r[8 + a] + l[12 + b] * r[12 + a]);
    }
  }

  float* orow = out;
  float* ocol = out + T;
  float* oval = out + 2 * T;
  long long blkbase = 16LL * base + 4LL * k0;
  float cf = (float)(v * 4);
#pragma unroll
  for (int a = 0; a < 4; a++) {
    long long rowbase = blkbase + (long long)a * 4 * cntu;
    float rf = (float)(u * 4 + a);
    if (m == 1) {
      *reinterpret_cast<float4*>(orow + rowbase) = make_float4(rf, rf, rf, rf);
      *reinterpret_cast<float4*>(ocol + rowbase) = make_float4(cf, cf + 1.0f, cf + 2.0f, cf + 3.0f);
      *reinterpret_cast<float4*>(oval + rowbase) =
          make_float4(val[a * 4 + 0], val[a * 4 + 1], val[a * 4 + 2], val[a * 4 + 3]);
    } else {
#pragma unroll
      for (int b = 0; b < 4; b++) {
        long long pos = rowbase + (long long)b * m + j;
        orow[pos] = rf;
        ocol[pos] = cf + (float)b;
        oval[pos] = val[a * 4 + b];
      }
    }
  }
}

extern "C" void kernel_launch(void* const* d_in, const int* in_sizes, int n_in,
                              void* d_out, int out_size, void* d_ws, size_t ws_size,
                              hipStream_t stream) {
  const float* maps = (const float*)d_in[0];
  const int* ei = (const int*)d_in[1];

  long long twoE = (long long)in_sizes[1] / 2;   // edge_index is (2, 2E)
  long long E = twoE / 2;
  long long T = (long long)out_size / 3;         // [rows(T), cols(T), vals(T)], float32
  long long totalBlocks = T / 16;                // n + 2E
  long long n = totalBlocks - twoE;
  if (n < 1 || n > N_MAX || totalBlocks > B_MAX || twoE > B_MAX) return;

  int iE = (int)E, i2E = (int)twoE, iN = (int)n, iB = (int)totalBlocks;
  int g2E = (i2E + THREADS - 1) / THREADS;
  int gD = (8 * iN + THREADS - 1) / THREADS;
  int gSort = (iN + 3) / 4;                      // 4 waves (nodes) per 256-thread block
  int gB = (iB + THREADS - 1) / THREADS;

  hist_kernel<<<g2E, THREADS, 0, stream>>>(ei, iE, i2E);
  scan_kernel<<<2, 1024, 0, stream>>>(iN);
  scatter_fill_kernel<<<g2E, THREADS, 0, stream>>>(ei, iE, i2E);
  diag_place_kernel<<<gD, THREADS, 0, stream>>>(maps, iN);
  sort_kernel<<<gSort, 256, 0, stream>>>(iN);
  emit_kernel<<<gB, THREADS, 0, stream>>>(maps, iE, T, iB, (float*)d_out);
}